// Round 11
// baseline (240.613 us; speedup 1.0000x reference)
//
#include <hip/hip_runtime.h>
#include <hip/hip_bf16.h>

#define NQ 2048
#define NB 2

typedef unsigned short u16;
typedef unsigned int u32;
typedef _Float16 f16;
typedef __attribute__((ext_vector_type(8))) _Float16 half8;
typedef __attribute__((ext_vector_type(2))) __fp16 fp16x2;
typedef __attribute__((ext_vector_type(4))) float f32x4;

#define MFMAH(A, B, C) __builtin_amdgcn_mfma_f32_16x16x32_f16(A, B, C, 0, 0, 0)

__device__ __forceinline__ u16 f2h(float x) {
    f16 h = (f16)x;                 // v_cvt_f16_f32 (RNE)
    return *(u16*)&h;
}
// packed f32x2 -> fp16x2 (v_cvt_pkrtz_f16_f32), returned as u32
__device__ __forceinline__ u32 pk_h2(float a, float b) {
    union { fp16x2 v; u32 u; } c;
    c.v = __builtin_amdgcn_cvt_pkrtz(a, b);
    return c.u;
}
// raw v_exp_f32 (2^x)
__device__ __forceinline__ float fexp2(float x) {
#if __has_builtin(__builtin_amdgcn_exp2f)
    return __builtin_amdgcn_exp2f(x);
#else
    return exp2f(x);
#endif
}
// async global->LDS DMA, 16B/lane; lds dest is wave-uniform base + lane*16
__device__ __forceinline__ void glds16(const u16* g, u16* l) {
    typedef const __attribute__((address_space(1))) u16 gu16;
    typedef __attribute__((address_space(3))) u16 lu16;
    __builtin_amdgcn_global_load_lds((gu16*)g, (lu16*)l, 16, 0, 0);
}

// q-scale: 1/sqrt(64) * log2(e), so attention scores land in log2 domain
#define QSCALE 0.18033688011112042f

// ============ merge to fp16: rows 0..3071 = q,k,v; 3072..4095 = o ============
// vectorized x4: each thread does 4 consecutive cols of one row.
__global__ __launch_bounds__(256) void merge_w16(
    const float* __restrict__ w0, const float* __restrict__ dw0, const float* __restrict__ db0,
    const float* __restrict__ w1, const float* __restrict__ dw1, const float* __restrict__ db1,
    const float* __restrict__ w2, const float* __restrict__ dw2, const float* __restrict__ db2,
    const float* __restrict__ w3, const float* __restrict__ dw3, const float* __restrict__ db3,
    u16* __restrict__ Wf) {
    int t = blockIdx.x * 256 + threadIdx.x;       // over 4096*256
    int row = t >> 8, c4 = (t & 255) << 2;
    int which = row >> 10, lr = row & 1023;
    const float* W  = (which == 0) ? w0  : (which == 1) ? w1  : (which == 2) ? w2  : w3;
    const float* dW = (which == 0) ? dw0 : (which == 1) ? dw1 : (which == 2) ? dw2 : dw3;
    const float* dB = (which == 0) ? db0 : (which == 1) ? db1 : (which == 2) ? db2 : db3;
    float4 acc = *(const float4*)&W[lr * 1024 + c4];
#pragma unroll
    for (int r = 0; r < 5; ++r) {
        float b = dB[lr * 5 + r];
        float4 d = *(const float4*)&dW[r * 1024 + c4];
        acc.x += b * d.x; acc.y += b * d.y; acc.z += b * d.z; acc.w += b * d.w;
    }
    if (which == 0) {
        acc.x *= QSCALE; acc.y *= QSCALE; acc.z *= QSCALE; acc.w *= QSCALE;
    }
    *(uint2*)&Wf[row * 1024 + c4] = make_uint2(pk_h2(acc.x, acc.y), pk_h2(acc.z, acc.w));
}

__global__ __launch_bounds__(256) void bias_pack(
    const float* __restrict__ b0, const float* __restrict__ b1,
    const float* __restrict__ b2, const float* __restrict__ b3,
    float* __restrict__ ball) {
    int t = blockIdx.x * 256 + threadIdx.x;   // 4096
    int which = t >> 10;
    const float* B = (which == 0) ? b0 : (which == 1) ? b1 : (which == 2) ? b2 : b3;
    float v = B[t & 1023];
    if (which == 0) v *= QSCALE;
    ball[t] = v;
}

// x -> single fp16 (RNE)
__global__ __launch_bounds__(256) void xcast(const float* __restrict__ x,
                                             u16* __restrict__ xf) {
    int i4 = (blockIdx.x * 256 + threadIdx.x) * 4;
    float4 v = *(const float4*)&x[i4];
    *(uint2*)&xf[i4] = make_uint2(pk_h2(v.x, v.y), pk_h2(v.z, v.w));
}

// ============ fp16 GEMM: C[4096][N] = A @ B^T + bias ============
// Single fp16 product. TM x 128 tile, BK=64 staged as two 32-col halves
// (each half keeps the packed [row][32] m97 bank layout), global_load_lds(16).
// If VtOut: column blocks bn >= 2048 (V third of fused QKV) store TRANSPOSED
// to VtOut[(col-2048)][4096].
template <int TM>
__global__ __launch_bounds__(256) void gemm_f16(
    const u16* __restrict__ Af, const u16* __restrict__ Bf,
    const float* __restrict__ bias,
    float* __restrict__ Cf, u16* __restrict__ Cb, int ldc,
    u16* __restrict__ VtOut) {
    constexpr int MI = TM / 32;               // m-subtiles per wave
    __shared__ u16 As[2][TM * 32];
    __shared__ u16 Bs[2][128 * 32];
    const int tid = threadIdx.x;
    const int wid = tid >> 6, lane = tid & 63;
    const int ln = lane & 15, quad = lane >> 4;
    const int bm = blockIdx.y * TM, bn = blockIdx.x * 128;
    const int wm = (wid >> 1) * (TM / 2), wn = (wid & 1) * 64;
    const int lrow = lane >> 2;               // DMA: row within 16-row group
    const int lchunk = (lane & 3) * 8;        // DMA: u16 offset of 16B chunk

    f32x4 acc[MI][4];
#pragma unroll
    for (int i = 0; i < MI; ++i)
#pragma unroll
        for (int j = 0; j < 4; ++j) acc[i][j] = (f32x4){0.f, 0.f, 0.f, 0.f};

    for (int k0 = 0; k0 < 1024; k0 += 64) {
#pragma unroll
        for (int hf = 0; hf < 2; ++hf) {
#pragma unroll
            for (int p = 0; p < TM / 64; ++p) {
                int r = p * 64 + wid * 16;
                glds16(&Af[(bm + r + lrow) * 1024 + k0 + hf * 32 + lchunk],
                       &As[hf][r * 32]);
            }
#pragma unroll
            for (int p = 0; p < 2; ++p) {
                int r = p * 64 + wid * 16;
                glds16(&Bf[(bn + r + lrow) * 1024 + k0 + hf * 32 + lchunk],
                       &Bs[hf][r * 32]);
            }
        }
        asm volatile("s_waitcnt vmcnt(0)" ::: "memory");
        __syncthreads();

        half8 a[MI][2], b[4][2];
#pragma unroll
        for (int kc = 0; kc < 2; ++kc) {
#pragma unroll
            for (int j = 0; j < 4; ++j)
                b[j][kc] = *(const half8*)&Bs[kc][(wn + j * 16 + ln) * 32 + quad * 8];
#pragma unroll
            for (int i = 0; i < MI; ++i)
                a[i][kc] = *(const half8*)&As[kc][(wm + i * 16 + ln) * 32 + quad * 8];
        }
#pragma unroll
        for (int i = 0; i < MI; ++i)
#pragma unroll
            for (int j = 0; j < 4; ++j) {
                acc[i][j] = MFMAH(a[i][0], b[j][0], acc[i][j]);
                acc[i][j] = MFMAH(a[i][1], b[j][1], acc[i][j]);
            }
        __syncthreads();
    }

    if (VtOut && bn >= 2048) {
        // transposed store: VtOut[d][seq]; lane holds 4 consecutive seq rows.
#pragma unroll
        for (int i = 0; i < MI; ++i)
#pragma unroll
            for (int j = 0; j < 4; ++j) {
                int col = bn + wn + j * 16 + ln;
                float bv = bias[col];
                int colV = col - 2048;
                int row0 = bm + wm + i * 16 + quad * 4;
                ushort4 pk = make_ushort4(f2h(acc[i][j][0] + bv), f2h(acc[i][j][1] + bv),
                                          f2h(acc[i][j][2] + bv), f2h(acc[i][j][3] + bv));
                *(ushort4*)&VtOut[colV * 4096 + row0] = pk;
            }
        return;
    }

#pragma unroll
    for (int i = 0; i < MI; ++i)
#pragma unroll
        for (int j = 0; j < 4; ++j) {
            int col = bn + wn + j * 16 + ln;
            float bv = bias[col];
#pragma unroll
            for (int r = 0; r < 4; ++r) {
                int row = bm + wm + i * 16 + quad * 4 + r;
                float v = acc[i][j][r] + bv;
                if (Cb) Cb[row * ldc + col] = f2h(v);
                else    Cf[row * ldc + col] = v;
            }
        }
}

// ============ flash attention, fp16 MFMA, transposed S/O ============
// Block: 4 waves x 16 q-rows = 64 q of one (b,h) -> grid 1024 (4/CU demanded,
// 3/CU resident at 45KB LDS = 12 waves/CU). 64-key tiles, register-prefetch
// double buffer, 1 barrier/tile. Scores in log2 domain (q pre-scaled by
// log2e/8) -> p = v_exp_f32 raw. Row sums via ones-MFMA.
// P: per-wave packed [qrow][64] u16 with XOR bank swizzle.
__global__ __launch_bounds__(256) void flash_f16(
    const u16* __restrict__ QKV, const u16* __restrict__ Vt,
    u16* __restrict__ AO) {
    __shared__ u16 Ks[2][64 * 72];     // [key][d], stride 72
    __shared__ u16 Vs[2][64 * 72];     // [d][key], stride 72
    __shared__ u16 Ps[4][16 * 64];     // per-wave [qrow][key], packed + swizzled

    const int tid = threadIdx.x;
    const int wid = tid >> 6, lane = tid & 63;
    const int ln = lane & 15, quad = lane >> 4;
    const int qt = blockIdx.x, h = blockIdx.y, b = blockIdx.z;
    const int rowbase = b * NQ;
    const int col0 = h * 64;
    const int q0 = rowbase + qt * 64 + wid * 16;   // wave's 16 q rows

    const half8 ones = {(f16)1, (f16)1, (f16)1, (f16)1,
                        (f16)1, (f16)1, (f16)1, (f16)1};

    // Q fragments (B-operand: lane ln = q-row q0+ln, k = kc*32+quad*8+j)
    half8 qf[2];
#pragma unroll
    for (int kc = 0; kc < 2; ++kc)
        qf[kc] = *(const half8*)&QKV[(q0 + ln) * 3072 + col0 + kc * 32 + quad * 8];

    f32x4 accO[4];       // [a: d-subtile], element (d=a*16+quad*4+r, q=ln)
    f32x4 accS = (f32x4){0.f, 0.f, 0.f, 0.f};
#pragma unroll
    for (int a = 0; a < 4; ++a) accO[a] = (f32x4){0.f, 0.f, 0.f, 0.f};

    const int srow = tid >> 2;          // 0..63
    const int sc0 = (tid & 3) * 16;     // 0,16,32,48
    const int NT = NQ / 64;
    const int swz = ln & 7;

    // stage tile 0
    {
        const u16* kg = QKV + (rowbase + srow) * 3072 + 1024 + col0;
        const u16* vg = Vt + (col0 + srow) * 4096 + rowbase;
        *(uint4*)&Ks[0][srow * 72 + sc0]     = *(const uint4*)&kg[sc0];
        *(uint4*)&Ks[0][srow * 72 + sc0 + 8] = *(const uint4*)&kg[sc0 + 8];
        *(uint4*)&Vs[0][srow * 72 + sc0]     = *(const uint4*)&vg[sc0];
        *(uint4*)&Vs[0][srow * 72 + sc0 + 8] = *(const uint4*)&vg[sc0 + 8];
    }
    __syncthreads();

    for (int kt = 0; kt < NT; ++kt) {
        const int cur = kt & 1;
        uint4 nk0, nk1, nv0, nv1;
        if (kt + 1 < NT) {
            const u16* kg = QKV + (rowbase + (kt + 1) * 64 + srow) * 3072 + 1024 + col0;
            const u16* vg = Vt + (col0 + srow) * 4096 + rowbase + (kt + 1) * 64;
            nk0 = *(const uint4*)&kg[sc0];
            nk1 = *(const uint4*)&kg[sc0 + 8];
            nv0 = *(const uint4*)&vg[sc0];
            nv1 = *(const uint4*)&vg[sc0 + 8];
        }

        // S^T = K @ Q^T : element (key = a*16+quad*4+r, q = ln)
        f32x4 s[4];
#pragma unroll
        for (int a = 0; a < 4; ++a) {
            half8 kf0 = *(const half8*)&Ks[cur][(a * 16 + ln) * 72 + quad * 8];
            half8 kf1 = *(const half8*)&Ks[cur][(a * 16 + ln) * 72 + 32 + quad * 8];
            f32x4 t = (f32x4){0.f, 0.f, 0.f, 0.f};
            t = MFMAH(kf0, qf[0], t);
            t = MFMAH(kf1, qf[1], t);
            s[a] = t;
        }

        // p = 2^s: one 8B swizzled LDS write per a
#pragma unroll
        for (int a = 0; a < 4; ++a) {
            float p0 = fexp2(s[a][0]), p1 = fexp2(s[a][1]);
            float p2 = fexp2(s[a][2]), p3 = fexp2(s[a][3]);
            uint2 w = make_uint2(pk_h2(p0, p1), pk_h2(p2, p3));
            int chunk = 2 * a + (quad >> 1);
            int addr = ln * 64 + ((chunk ^ swz) << 3) + ((quad & 1) << 2);
            *(uint2*)&Ps[wid][addr] = w;
        }

        asm volatile("s_waitcnt lgkmcnt(0)" ::: "memory");   // P visible wave-wide

        // P fragments (B-operand, swizzled b128 reads) + row sums via ones-MFMA
        half8 pf[2];
#pragma unroll
        for (int kc = 0; kc < 2; ++kc) {
            int chunk = kc * 4 + quad;
            pf[kc] = *(const half8*)&Ps[wid][ln * 64 + ((chunk ^ swz) << 3)];
            accS = MFMAH(ones, pf[kc], accS);
        }

        // O^T += V^T @ P^T : element (d = a*16+quad*4+r, q = ln)
#pragma unroll
        for (int a = 0; a < 4; ++a) {
            half8 vf0 = *(const half8*)&Vs[cur][(a * 16 + ln) * 72 + quad * 8];
            half8 vf1 = *(const half8*)&Vs[cur][(a * 16 + ln) * 72 + 32 + quad * 8];
            accO[a] = MFMAH(vf0, pf[0], accO[a]);
            accO[a] = MFMAH(vf1, pf[1], accO[a]);
        }

        if (kt + 1 < NT) {
            const int nb = cur ^ 1;
            *(uint4*)&Ks[nb][srow * 72 + sc0]     = nk0;
            *(uint4*)&Ks[nb][srow * 72 + sc0 + 8] = nk1;
            *(uint4*)&Vs[nb][srow * 72 + sc0]     = nv0;
            *(uint4*)&Vs[nb][srow * 72 + sc0 + 8] = nv1;
        }
        __syncthreads();
    }

    // epilogue: normalize (inv uniform per lane), single fp16 AO, ushort4 stores
    {
        float inv = 1.f / accS[0];
        int q = q0 + ln;
#pragma unroll
        for (int a = 0; a < 4; ++a) {
            ushort4 pk = make_ushort4(f2h(accO[a][0] * inv),
                                      f2h(accO[a][1] * inv),
                                      f2h(accO[a][2] * inv),
                                      f2h(accO[a][3] * inv));
            *(ushort4*)&AO[q * 1024 + col0 + a * 16 + quad * 4] = pk;
        }
    }
}

// ============ launch ============
extern "C" void kernel_launch(void* const* d_in, const int* in_sizes, int n_in,
                              void* d_out, int out_size, void* d_ws, size_t ws_size,
                              hipStream_t stream) {
    const float* x = (const float*)d_in[0];
    const float* w[4]  = {(const float*)d_in[1],  (const float*)d_in[5],
                          (const float*)d_in[9],  (const float*)d_in[13]};
    const float* bv[4] = {(const float*)d_in[2],  (const float*)d_in[6],
                          (const float*)d_in[10], (const float*)d_in[14]};
    const float* dw[4] = {(const float*)d_in[3],  (const float*)d_in[7],
                          (const float*)d_in[11], (const float*)d_in[15]};
    const float* db[4] = {(const float*)d_in[4],  (const float*)d_in[8],
                          (const float*)d_in[12], (const float*)d_in[16]};

    u16* p = (u16*)d_ws;
    u16* Wf  = p; p += 4096 * 1024;
    u16* xf  = p; p += 4096 * 1024;
    u16* QKV = p; p += 4096 * 3072;   // V third unused (lives in Vt)
    u16* Vt  = p; p += 1024 * 4096;
    float* ball = (float*)p;          // 4096 floats
    // AO aliases xf: x is dead after the QKV GEMM completes (same stream).
    u16* AO = xf;

    merge_w16<<<4096, 256, 0, stream>>>(w[0], dw[0], db[0], w[1], dw[1], db[1],
                                        w[2], dw[2], db[2], w[3], dw[3], db[3], Wf);
    bias_pack<<<16, 256, 0, stream>>>(bv[0], bv[1], bv[2], bv[3], ball);
    xcast<<<4096, 256, 0, stream>>>(x, xf);

    // fused q,k,v projection: q,k -> QKV fp16 row-major; v -> Vt transposed
    gemm_f16<128><<<dim3(24, 32), 256, 0, stream>>>(xf, Wf, ball,
                                                    nullptr, QKV, 3072, Vt);

    flash_f16<<<dim3(NQ / 64, 16, NB), 256, 0, stream>>>(QKV, Vt, AO);

    // o projection: fp32 out, TM=64 -> 512 blocks (2 blocks/CU)
    gemm_f16<64><<<dim3(8, 64), 256, 0, stream>>>(AO, Wf + 3072 * 1024,
                                                  ball + 3072, (float*)d_out, nullptr, 1024,
                                                  nullptr);
}